// Round 1
// baseline (826.394 us; speedup 1.0000x reference)
//
#include <hip/hip_runtime.h>
#include <hip/hip_bf16.h>
#include <stdint.h>

// DRNN_75204877353433: windowed bidirectional GRU (W=15) + BN + MLP + masked maxpool + linear
// B=32 S=512 W=15 E=300 H=256 V=50000 C=2, G=3H=768

typedef unsigned short u16;
typedef float f32x16 __attribute__((ext_vector_type(16)));
typedef short bf16x8 __attribute__((ext_vector_type(8)));

#define MFMA32 __builtin_amdgcn_mfma_f32_32x32x16_bf16

#define NB 32
#define NS 512
#define NW 15
#define NE 300
#define NH 256
#define NG 768
#define NCELL (NB*NS)   // 16384
#define EPAD 320        // E padded to multiple of 16 for K-loop
#define MR 64           // rows (cells/tokens) per block tile

__device__ __forceinline__ float bf2f(u16 u){
    union { unsigned int i; float f; } v; v.i = ((unsigned int)u) << 16; return v.f;
}
__device__ __forceinline__ u16 f2bf(float f){
    union { float f; unsigned int i; } v; v.f = f;
    unsigned int x = v.i;
    x += 0x7fffu + ((x >> 16) & 1u);   // RNE
    return (u16)(x >> 16);
}
__device__ __forceinline__ float sigm(float x){ return 1.0f/(1.0f + __expf(-x)); }
__device__ __forceinline__ float tanh_(float x){ return 1.0f - 2.0f/(1.0f + __expf(2.0f*x)); }
__device__ __forceinline__ unsigned fkey(float f){   // order-preserving float->uint map
    unsigned b = __float_as_uint(f);
    return b ^ ((b & 0x80000000u) ? 0xFFFFFFFFu : 0x80000000u);
}

// ---------------- prep: bf16 weight conversion + zero-init of accumulators ----------------
__global__ void prep_kernel(const float* __restrict__ Wih_f, const float* __restrict__ Wih_b,
                            const float* __restrict__ Whh_f, const float* __restrict__ Whh_b,
                            const float* __restrict__ mlpW,
                            u16* __restrict__ WihF_p, u16* __restrict__ WihB_p,
                            u16* __restrict__ WhhF_p, u16* __restrict__ WhhB_p,
                            u16* __restrict__ mlpW_p,
                            float* __restrict__ bnSum, float* __restrict__ bnSumSq,
                            unsigned* __restrict__ pooled_u)
{
    const int tid  = blockIdx.x*blockDim.x + threadIdx.x;
    const int nthr = gridDim.x*blockDim.x;
    for (int i = tid; i < NG*EPAD; i += nthr){
        int g = i / EPAD, k = i % EPAD;
        WihF_p[i] = (k < NE) ? f2bf(Wih_f[g*NE + k]) : (u16)0;
        WihB_p[i] = (k < NE) ? f2bf(Wih_b[g*NE + k]) : (u16)0;
    }
    for (int i = tid; i < NG*NH; i += nthr){ WhhF_p[i] = f2bf(Whh_f[i]); WhhB_p[i] = f2bf(Whh_b[i]); }
    for (int i = tid; i < 512*512; i += nthr) mlpW_p[i] = f2bf(mlpW[i]);
    for (int i = tid; i < 512; i += nthr){ bnSum[i] = 0.0f; bnSumSq[i] = 0.0f; }
    for (int i = tid; i < NB*512; i += nthr) pooled_u[i] = 0u;
}

// ---------------- eproj: xproj[token][g] = W_ih @ emb[tok] + b_ih (bf16 out) ----------------
// rows 0..16383 = real tokens, rows 16384..16447 = pad token (id 0)
__global__ __launch_bounds__(512, 2)
void eproj_kernel(const int* __restrict__ x, const float* __restrict__ emb,
                  const u16* __restrict__ Wih_p, const float* __restrict__ b_ih,
                  u16* __restrict__ xproj)
{
    __shared__ u16 a_lds[MR*328];     // 64 rows x 320(+8 pad) bf16 of gathered embeddings
    const int tid = threadIdx.x;
    const int mb  = blockIdx.x;       // 0..256
    {
        const int row = tid >> 3, jj = tid & 7;
        const int flat = mb*MR + row;
        const int t_id = (flat < NCELL) ? x[flat] : 0;
        const float4* src = (const float4*)(emb + (size_t)t_id*NE);
        u16* dst = a_lds + row*328;
        for (int idx = jj; idx < 75; idx += 8){   // 300 floats = 75 float4
            float4 v = src[idx];
            ushort4 o; o.x=f2bf(v.x); o.y=f2bf(v.y); o.z=f2bf(v.z); o.w=f2bf(v.w);
            *(ushort4*)(dst + idx*4) = o;
        }
        if (jj == 7){
            const ushort4 z = {0,0,0,0};
            #pragma unroll
            for (int c = 300; c < 320; c += 4) *(ushort4*)(dst + c) = z;
        }
    }
    __syncthreads();

    const int lane = tid & 63, wv = tid >> 6, l31 = lane & 31, q = lane >> 5;
    f32x16 acc[2][3];
    #pragma unroll
    for (int a = 0; a < 2; a++)
        #pragma unroll
        for (int g = 0; g < 3; g++)
            #pragma unroll
            for (int i = 0; i < 16; i++) acc[a][g][i] = 0.0f;

    const u16* a0p = a_lds + l31*328 + q*8;
    const u16* a1p = a0p + 32*328;
    const u16* b0p = Wih_p + (size_t)(wv*96 +  0 + l31)*EPAD + q*8;
    const u16* b1p = Wih_p + (size_t)(wv*96 + 32 + l31)*EPAD + q*8;
    const u16* b2p = Wih_p + (size_t)(wv*96 + 64 + l31)*EPAD + q*8;

    #pragma unroll 4
    for (int kc = 0; kc < 20; kc++){
        const int ko = kc*16;
        bf16x8 a0 = *(const bf16x8*)(a0p + ko);
        bf16x8 a1 = *(const bf16x8*)(a1p + ko);
        bf16x8 b0 = *(const bf16x8*)(b0p + ko);
        bf16x8 b1 = *(const bf16x8*)(b1p + ko);
        bf16x8 b2 = *(const bf16x8*)(b2p + ko);
        acc[0][0] = MFMA32(a0,b0,acc[0][0],0,0,0);
        acc[0][1] = MFMA32(a0,b1,acc[0][1],0,0,0);
        acc[0][2] = MFMA32(a0,b2,acc[0][2],0,0,0);
        acc[1][0] = MFMA32(a1,b0,acc[1][0],0,0,0);
        acc[1][1] = MFMA32(a1,b1,acc[1][1],0,0,0);
        acc[1][2] = MFMA32(a1,b2,acc[1][2],0,0,0);
    }
    #pragma unroll
    for (int nt = 0; nt < 3; nt++){
        const int colg = wv*96 + nt*32 + l31;
        const float bias = b_ih[colg];
        #pragma unroll
        for (int mi = 0; mi < 2; mi++){
            #pragma unroll
            for (int r = 0; r < 16; r++){
                const int rit = (r&3) + 8*(r>>2) + 4*q + mi*32;   // C/D row layout (32x32)
                xproj[(size_t)(mb*MR + rit)*NG + colg] = f2bf(acc[mi][nt][r] + bias);
            }
        }
    }
}

// ---------------- recurrence: per-block 64 cells, all 15 GRU steps, h persistent in regs ----------------
__global__ __launch_bounds__(512, 2)
void recur_kernel(const int* __restrict__ x, const u16* __restrict__ xproj,
                  const u16* __restrict__ Whh_p, const float* __restrict__ b_hh,
                  u16* __restrict__ hidden, float* __restrict__ bnSum, float* __restrict__ bnSumSq,
                  int dir)
{
    __shared__ u16 h_lds[MR*264];     // 64 x 256(+8 pad) bf16 — A-operand staging
    __shared__ float maskv[MR];
    const int tid = threadIdx.x;
    const int mb  = blockIdx.x;       // 0..255
    if (tid < MR) maskv[tid] = (x[mb*MR + tid] > 0) ? 1.0f : 0.0f;
    __syncthreads();

    const int lane = tid & 63, wv = tid >> 6, l31 = lane & 31, q = lane >> 5;
    const int col  = wv*32 + l31;            // hidden column 0..255 (per-lane constant)
    const int bidx = (mb*MR) >> 9;
    const int s0   = (mb*MR) & (NS-1);

    const float bhr = b_hh[col];
    const float bhz = b_hh[NH  + col];
    const float bhn = b_hh[2*NH + col];

    const u16* ha0 = h_lds + l31*264 + q*8;
    const u16* ha1 = ha0 + 32*264;
    const u16* wb0 = Whh_p + (size_t)(col       )*NH + q*8;
    const u16* wb1 = Whh_p + (size_t)(NH  + col )*NH + q*8;
    const u16* wb2 = Whh_p + (size_t)(2*NH + col)*NH + q*8;

    float hreg[32];
    #pragma unroll
    for (int i = 0; i < 32; i++) hreg[i] = 0.0f;

    #pragma unroll 1
    for (int t = 0; t < NW; t++){
        f32x16 acc[2][3];
        #pragma unroll
        for (int a = 0; a < 2; a++)
            #pragma unroll
            for (int g = 0; g < 3; g++)
                #pragma unroll
                for (int i = 0; i < 16; i++) acc[a][g][i] = 0.0f;

        if (t > 0){
            #pragma unroll 2
            for (int kc = 0; kc < 16; kc++){
                const int ko = kc*16;
                bf16x8 a0 = *(const bf16x8*)(ha0 + ko);
                bf16x8 a1 = *(const bf16x8*)(ha1 + ko);
                bf16x8 b0 = *(const bf16x8*)(wb0 + ko);   // W_hh streamed from L2
                bf16x8 b1 = *(const bf16x8*)(wb1 + ko);
                bf16x8 b2 = *(const bf16x8*)(wb2 + ko);
                acc[0][0] = MFMA32(a0,b0,acc[0][0],0,0,0);
                acc[0][1] = MFMA32(a0,b1,acc[0][1],0,0,0);
                acc[0][2] = MFMA32(a0,b2,acc[0][2],0,0,0);
                acc[1][0] = MFMA32(a1,b0,acc[1][0],0,0,0);
                acc[1][1] = MFMA32(a1,b1,acc[1][1],0,0,0);
                acc[1][2] = MFMA32(a1,b2,acc[1][2],0,0,0);
            }
        }
        // gate phase (fp32): r=sig(xr+hr) z=sig(xz+hz) n=tanh(xn+r*hn) h=(1-z)n+zh
        #pragma unroll
        for (int mi = 0; mi < 2; mi++){
            #pragma unroll
            for (int r = 0; r < 16; r++){
                const int rit = (r&3) + 8*(r>>2) + 4*q + mi*32;
                const int s = s0 + rit;
                const int j = (dir == 0) ? (s - (NW-1) + t) : (s + (NW-1) - t);
                const int rj = ((unsigned)j < (unsigned)NS) ? (bidx*NS + j) : NCELL; // pad row
                const u16* xp = xproj + (size_t)rj*NG + col;
                const float xr = bf2f(xp[0]);
                const float xz = bf2f(xp[NH]);
                const float xn = bf2f(xp[2*NH]);
                const float rg  = sigm(xr + acc[mi][0][r] + bhr);
                const float zg  = sigm(xz + acc[mi][1][r] + bhz);
                const float ngt = tanh_(xn + rg*(acc[mi][2][r] + bhn));
                hreg[mi*16+r] = (1.0f - zg)*ngt + zg*hreg[mi*16+r];
            }
        }
        __syncthreads();                       // all A-frag reads of this step done
        #pragma unroll
        for (int mi = 0; mi < 2; mi++)
            #pragma unroll
            for (int r = 0; r < 16; r++){
                const int rit = (r&3) + 8*(r>>2) + 4*q + mi*32;
                h_lds[rit*264 + col] = f2bf(hreg[mi*16+r]);
            }
        __syncthreads();                       // h_lds ready for next step
    }
    // epilogue: mask, store hidden (bf16), BN partial sums
    float sum = 0.0f, sumsq = 0.0f;
    #pragma unroll
    for (int mi = 0; mi < 2; mi++)
        #pragma unroll
        for (int r = 0; r < 16; r++){
            const int rit = (r&3) + 8*(r>>2) + 4*q + mi*32;
            const float hm = hreg[mi*16+r] * maskv[rit];
            hidden[(size_t)(mb*MR + rit)*512 + dir*NH + col] = f2bf(hm);
            sum += hm; sumsq += hm*hm;
        }
    sum   += __shfl_xor(sum, 32);
    sumsq += __shfl_xor(sumsq, 32);
    if (q == 0){
        atomicAdd(&bnSum[dir*NH + col], sum);
        atomicAdd(&bnSumSq[dir*NH + col], sumsq);
    }
}

// ---------------- BN finalize: per-channel scale/shift ----------------
__global__ void bnfin_kernel(const float* __restrict__ bnSum, const float* __restrict__ bnSumSq,
                             const float* __restrict__ gamma, const float* __restrict__ beta,
                             float* __restrict__ bnScale, float* __restrict__ bnShift)
{
    const int c = blockIdx.x*blockDim.x + threadIdx.x;
    if (c < 512){
        const float mu  = bnSum[c]   * (1.0f/16384.0f);
        const float var = bnSumSq[c] * (1.0f/16384.0f) - mu*mu;
        const float inv = rsqrtf(var + 1e-5f);
        const float sc  = gamma[c]*inv;
        bnScale[c] = sc;
        bnShift[c] = beta[c] - mu*sc;
    }
}

// ---------------- MLP + mask + max-pool (atomic ordered-uint max) ----------------
__global__ __launch_bounds__(512, 2)
void mlp_kernel(const int* __restrict__ x, const u16* __restrict__ hidden,
                const u16* __restrict__ mlpW_p, const float* __restrict__ bnScale,
                const float* __restrict__ bnShift, const float* __restrict__ mlp_b,
                unsigned* __restrict__ pooled_u)
{
    __shared__ u16 a_lds[MR*520];   // 64 x 512(+8) bf16 normalized+masked hidden
    __shared__ float maskv[MR];
    const int tid = threadIdx.x;
    const int mb  = blockIdx.x;     // 0..255
    if (tid < MR) maskv[tid] = (x[mb*MR + tid] > 0) ? 1.0f : 0.0f;
    __syncthreads();
    {
        const int row = tid >> 3, jj = tid & 7;
        const float m = maskv[row];
        const u16* src = hidden + (size_t)(mb*MR + row)*512;
        u16* dst = a_lds + row*520;
        for (int c4 = jj; c4 < 128; c4 += 8){
            ushort4 v = ((const ushort4*)src)[c4];
            const int c = c4*4;
            float4 sc = *(const float4*)(bnScale + c);
            float4 sh = *(const float4*)(bnShift + c);
            ushort4 o;
            o.x = f2bf((bf2f(v.x)*sc.x + sh.x)*m);
            o.y = f2bf((bf2f(v.y)*sc.y + sh.y)*m);
            o.z = f2bf((bf2f(v.z)*sc.z + sh.z)*m);
            o.w = f2bf((bf2f(v.w)*sc.w + sh.w)*m);
            *(ushort4*)(dst + c) = o;
        }
    }
    __syncthreads();

    const int lane = tid & 63, wv = tid >> 6, l31 = lane & 31, q = lane >> 5;
    f32x16 acc[2][2];
    #pragma unroll
    for (int a = 0; a < 2; a++)
        #pragma unroll
        for (int g = 0; g < 2; g++)
            #pragma unroll
            for (int i = 0; i < 16; i++) acc[a][g][i] = 0.0f;

    const u16* a0p = a_lds + l31*520 + q*8;
    const u16* a1p = a0p + 32*520;
    const u16* b0p = mlpW_p + (size_t)(wv*64 +      l31)*512 + q*8;
    const u16* b1p = mlpW_p + (size_t)(wv*64 + 32 + l31)*512 + q*8;

    #pragma unroll 4
    for (int kc = 0; kc < 32; kc++){
        const int ko = kc*16;
        bf16x8 a0 = *(const bf16x8*)(a0p + ko);
        bf16x8 a1 = *(const bf16x8*)(a1p + ko);
        bf16x8 b0 = *(const bf16x8*)(b0p + ko);
        bf16x8 b1 = *(const bf16x8*)(b1p + ko);
        acc[0][0] = MFMA32(a0,b0,acc[0][0],0,0,0);
        acc[0][1] = MFMA32(a0,b1,acc[0][1],0,0,0);
        acc[1][0] = MFMA32(a1,b0,acc[1][0],0,0,0);
        acc[1][1] = MFMA32(a1,b1,acc[1][1],0,0,0);
    }

    const int bidx = mb >> 3;   // 8 row-blocks per batch element
    #pragma unroll
    for (int nt = 0; nt < 2; nt++){
        const int colg = wv*64 + nt*32 + l31;
        const float bias = mlp_b[colg];
        float mx = -3.4e38f;
        #pragma unroll
        for (int mi = 0; mi < 2; mi++)
            #pragma unroll
            for (int r = 0; r < 16; r++){
                const int rit = (r&3) + 8*(r>>2) + 4*q + mi*32;
                const float m = maskv[rit];
                const float v = (acc[mi][nt][r] + bias)*m + (m - 1.0f)*65500.0f;
                mx = fmaxf(mx, v);
            }
        mx = fmaxf(mx, __shfl_xor(mx, 32));
        if (q == 0) atomicMax(&pooled_u[bidx*512 + colg], fkey(mx));
    }
}

// ---------------- final linear [32x512] @ [512x2] ----------------
__global__ void final_kernel(const unsigned* __restrict__ pooled_u,
                             const float* __restrict__ linW, const float* __restrict__ linb,
                             float* __restrict__ out)
{
    const int b = blockIdx.x;       // 32
    const int lane = threadIdx.x;   // 64
    float s0 = 0.0f, s1 = 0.0f;
    for (int c = lane; c < 512; c += 64){
        const unsigned u = pooled_u[b*512 + c];
        const unsigned bits = (u & 0x80000000u) ? (u ^ 0x80000000u) : ~u;
        const float f = __uint_as_float(bits);
        s0 += f * linW[c];
        s1 += f * linW[512 + c];
    }
    #pragma unroll
    for (int off = 32; off > 0; off >>= 1){
        s0 += __shfl_xor(s0, off);
        s1 += __shfl_xor(s1, off);
    }
    if (lane == 0){ out[2*b] = s0 + linb[0]; out[2*b + 1] = s1 + linb[1]; }
}

extern "C" void kernel_launch(void* const* d_in, const int* in_sizes, int n_in,
                              void* d_out, int out_size, void* d_ws, size_t ws_size,
                              hipStream_t stream)
{
    const int*   x     = (const int*)  d_in[0];
    const float* emb   = (const float*)d_in[5];
    const float* Wih_f = (const float*)d_in[6];
    const float* Whh_f = (const float*)d_in[7];
    const float* bih_f = (const float*)d_in[8];
    const float* bhh_f = (const float*)d_in[9];
    const float* Wih_b = (const float*)d_in[10];
    const float* Whh_b = (const float*)d_in[11];
    const float* bih_b = (const float*)d_in[12];
    const float* bhh_b = (const float*)d_in[13];
    const float* gamma = (const float*)d_in[14];
    const float* beta  = (const float*)d_in[15];
    const float* mlpW  = (const float*)d_in[16];
    const float* mlpb  = (const float*)d_in[17];
    const float* linW  = (const float*)d_in[18];
    const float* linb  = (const float*)d_in[19];
    float* out = (float*)d_out;
    char* ws = (char*)d_ws;

    // workspace layout (44.4 MB total; xproj buffer shared by both directions)
    u16*   WihF_p  = (u16*)  (ws + 0);
    u16*   WihB_p  = (u16*)  (ws + 491520);
    u16*   WhhF_p  = (u16*)  (ws + 983040);
    u16*   WhhB_p  = (u16*)  (ws + 1376256);
    u16*   mlpW_p  = (u16*)  (ws + 1769472);
    float* bnSum   = (float*)(ws + 2293760);
    float* bnSumSq = (float*)(ws + 2295808);
    float* bnScale = (float*)(ws + 2297856);
    float* bnShift = (float*)(ws + 2299904);
    unsigned* pooled_u = (unsigned*)(ws + 2301952);
    u16*   hidden  = (u16*)  (ws + 2367488);    // 16384x512 bf16
    u16*   xproj   = (u16*)  (ws + 19144704);   // 16448x768 bf16 (shared F then B)

    prep_kernel<<<512, 256, 0, stream>>>(Wih_f, Wih_b, Whh_f, Whh_b, mlpW,
                                         WihF_p, WihB_p, WhhF_p, WhhB_p, mlpW_p,
                                         bnSum, bnSumSq, pooled_u);
    // forward direction
    eproj_kernel<<<257, 512, 0, stream>>>(x, emb, WihF_p, bih_f, xproj);
    recur_kernel<<<256, 512, 0, stream>>>(x, xproj, WhhF_p, bhh_f, hidden, bnSum, bnSumSq, 0);
    // backward direction (reuses xproj buffer)
    eproj_kernel<<<257, 512, 0, stream>>>(x, emb, WihB_p, bih_b, xproj);
    recur_kernel<<<256, 512, 0, stream>>>(x, xproj, WhhB_p, bhh_b, hidden, bnSum, bnSumSq, 1);

    bnfin_kernel<<<2, 256, 0, stream>>>(bnSum, bnSumSq, gamma, beta, bnScale, bnShift);
    mlp_kernel<<<256, 512, 0, stream>>>(x, hidden, mlpW_p, bnScale, bnShift, mlpb, pooled_u);
    final_kernel<<<32, 64, 0, stream>>>(pooled_u, linW, linb, out);
}

// Round 2
// 800.628 us; speedup vs baseline: 1.0322x; 1.0322x over previous
//
#include <hip/hip_runtime.h>
#include <hip/hip_bf16.h>
#include <stdint.h>

// DRNN_75204877353433: windowed bidirectional GRU (W=15) + BN + MLP + masked maxpool + linear
// B=32 S=512 W=15 E=300 H=256 V=50000 C=2, G=3H=768

typedef unsigned short u16;
typedef float f32x16 __attribute__((ext_vector_type(16)));
typedef short bf16x8 __attribute__((ext_vector_type(8)));

#define MFMA32 __builtin_amdgcn_mfma_f32_32x32x16_bf16

#define NB 32
#define NS 512
#define NW 15
#define NE 300
#define NH 256
#define NG 768
#define NCELL (NB*NS)   // 16384
#define EPAD 320        // E padded to multiple of 16 for K-loop
#define MR 64           // rows (cells/tokens) per block tile

__device__ __forceinline__ float bf2f(u16 u){
    union { unsigned int i; float f; } v; v.i = ((unsigned int)u) << 16; return v.f;
}
__device__ __forceinline__ u16 f2bf(float f){
    union { float f; unsigned int i; } v; v.f = f;
    unsigned int x = v.i;
    x += 0x7fffu + ((x >> 16) & 1u);   // RNE
    return (u16)(x >> 16);
}
__device__ __forceinline__ u16 f2bf_rh(float f){   // round-half-up, 2 VALU ops
    return (u16)((__float_as_uint(f) + 0x8000u) >> 16);
}
__device__ __forceinline__ unsigned fkey(float f){   // order-preserving float->uint map
    unsigned b = __float_as_uint(f);
    return b ^ ((b & 0x80000000u) ? 0xFFFFFFFFu : 0x80000000u);
}

// ---- full-rate gate math: no v_exp/v_rcp/IEEE-div (those were 44% VALUBusy) ----
__device__ __forceinline__ float exp2_poly(float f){   // 2^f, f in [-0.5,0.5], err ~2e-6
    float p = 1.33336e-3f;
    p = fmaf(p, f, 9.61812e-3f);
    p = fmaf(p, f, 5.55041e-2f);
    p = fmaf(p, f, 2.40227e-1f);
    p = fmaf(p, f, 6.93147e-1f);
    p = fmaf(p, f, 1.0f);
    return p;
}
__device__ __forceinline__ float rcp1p_fast(float d){  // 1/d for d in [1, 2^30]
    float y = __uint_as_float(0x7EF311C3u - __float_as_uint(d));
    y = y * (2.0f - d*y);
    y = y * (2.0f - d*y);      // rel err ~1e-4
    return y;
}
__device__ __forceinline__ float sigm_fast(float x){   // 1/(1+e^-x)
    float t = x * -1.44269504f;
    t = fminf(fmaxf(t, -30.0f), 30.0f);
    float nf = __builtin_rintf(t);
    float e  = ldexpf(exp2_poly(t - nf), (int)nf);
    return rcp1p_fast(1.0f + e);
}
__device__ __forceinline__ float tanh_fast(float x){   // 2*sigm(2x)-1
    float t = x * -2.88539008f;
    t = fminf(fmaxf(t, -30.0f), 30.0f);
    float nf = __builtin_rintf(t);
    float e  = ldexpf(exp2_poly(t - nf), (int)nf);
    float s  = rcp1p_fast(1.0f + e);
    return fmaf(2.0f, s, -1.0f);
}

// ---------------- prep: bf16 weight conversion + zero-init of accumulators ----------------
__global__ void prep_kernel(const float* __restrict__ Wih_f, const float* __restrict__ Wih_b,
                            const float* __restrict__ Whh_f, const float* __restrict__ Whh_b,
                            const float* __restrict__ mlpW,
                            u16* __restrict__ WihF_p, u16* __restrict__ WihB_p,
                            u16* __restrict__ WhhF_p, u16* __restrict__ WhhB_p,
                            u16* __restrict__ mlpW_p,
                            float* __restrict__ bnSum, float* __restrict__ bnSumSq,
                            unsigned* __restrict__ pooled_u)
{
    const int tid  = blockIdx.x*blockDim.x + threadIdx.x;
    const int nthr = gridDim.x*blockDim.x;
    for (int i = tid; i < NG*EPAD; i += nthr){
        int g = i / EPAD, k = i % EPAD;
        WihF_p[i] = (k < NE) ? f2bf(Wih_f[g*NE + k]) : (u16)0;
        WihB_p[i] = (k < NE) ? f2bf(Wih_b[g*NE + k]) : (u16)0;
    }
    for (int i = tid; i < NG*NH; i += nthr){ WhhF_p[i] = f2bf(Whh_f[i]); WhhB_p[i] = f2bf(Whh_b[i]); }
    for (int i = tid; i < 512*512; i += nthr) mlpW_p[i] = f2bf(mlpW[i]);
    for (int i = tid; i < 512; i += nthr){ bnSum[i] = 0.0f; bnSumSq[i] = 0.0f; }
    for (int i = tid; i < NB*512; i += nthr) pooled_u[i] = 0u;
}

// ---------------- eproj: packed xprojP[row][col][{r,z,n,0}] bf16, b_hh_r/z folded in ----------------
// rows 0..16383 = real tokens, rows 16384..16447 = pad token (id 0)
__global__ __launch_bounds__(512, 2)
void eproj_kernel(const int* __restrict__ x, const float* __restrict__ emb,
                  const u16* __restrict__ Wih_p, const float* __restrict__ b_ih,
                  const float* __restrict__ b_hh, u16* __restrict__ xprojP)
{
    __shared__ u16 a_lds[MR*328];     // 64 rows x 320(+8 pad) bf16 of gathered embeddings
    const int tid = threadIdx.x;
    const int mb  = blockIdx.x;       // 0..256
    {
        const int row = tid >> 3, jj = tid & 7;
        const int flat = mb*MR + row;
        const int t_id = (flat < NCELL) ? x[flat] : 0;
        const float4* src = (const float4*)(emb + (size_t)t_id*NE);
        u16* dst = a_lds + row*328;
        for (int idx = jj; idx < 75; idx += 8){   // 300 floats = 75 float4
            float4 v = src[idx];
            ushort4 o; o.x=f2bf(v.x); o.y=f2bf(v.y); o.z=f2bf(v.z); o.w=f2bf(v.w);
            *(ushort4*)(dst + idx*4) = o;
        }
        if (jj == 7){
            const ushort4 z = {0,0,0,0};
            #pragma unroll
            for (int c = 300; c < 320; c += 4) *(ushort4*)(dst + c) = z;
        }
    }
    __syncthreads();

    const int lane = tid & 63, wv = tid >> 6, l31 = lane & 31, q = lane >> 5;
    const int col = wv*32 + l31;      // hidden column 0..255
    f32x16 acc[2][3];
    #pragma unroll
    for (int a = 0; a < 2; a++)
        #pragma unroll
        for (int g = 0; g < 3; g++)
            #pragma unroll
            for (int i = 0; i < 16; i++) acc[a][g][i] = 0.0f;

    const u16* a0p = a_lds + l31*328 + q*8;
    const u16* a1p = a0p + 32*328;
    const u16* b0p = Wih_p + (size_t)(         col)*EPAD + q*8;   // gate r plane
    const u16* b1p = Wih_p + (size_t)(NH     + col)*EPAD + q*8;   // gate z plane
    const u16* b2p = Wih_p + (size_t)(2*NH   + col)*EPAD + q*8;   // gate n plane

    #pragma unroll 4
    for (int kc = 0; kc < 20; kc++){
        const int ko = kc*16;
        bf16x8 a0 = *(const bf16x8*)(a0p + ko);
        bf16x8 a1 = *(const bf16x8*)(a1p + ko);
        bf16x8 b0 = *(const bf16x8*)(b0p + ko);
        bf16x8 b1 = *(const bf16x8*)(b1p + ko);
        bf16x8 b2 = *(const bf16x8*)(b2p + ko);
        acc[0][0] = MFMA32(a0,b0,acc[0][0],0,0,0);
        acc[0][1] = MFMA32(a0,b1,acc[0][1],0,0,0);
        acc[0][2] = MFMA32(a0,b2,acc[0][2],0,0,0);
        acc[1][0] = MFMA32(a1,b0,acc[1][0],0,0,0);
        acc[1][1] = MFMA32(a1,b1,acc[1][1],0,0,0);
        acc[1][2] = MFMA32(a1,b2,acc[1][2],0,0,0);
    }
    const float br  = b_ih[col]      + b_hh[col];        // fold recurrent bias (r,z)
    const float bz  = b_ih[NH+col]   + b_hh[NH+col];
    const float bn_ = b_ih[2*NH+col];                    // b_hh_n folded into recur acc init
    #pragma unroll
    for (int mi = 0; mi < 2; mi++){
        #pragma unroll
        for (int r = 0; r < 16; r++){
            const int rit = (r&3) + 8*(r>>2) + 4*q + mi*32;   // C/D row layout (32x32)
            const int row = mb*MR + rit;
            ushort4 o;
            o.x = f2bf(acc[mi][0][r] + br);
            o.y = f2bf(acc[mi][1][r] + bz);
            o.z = f2bf(acc[mi][2][r] + bn_);
            o.w = 0;
            *(ushort4*)(xprojP + (size_t)row*1024 + col*4) = o;
        }
    }
}

// ---------------- recurrence: per-block 64 cells, all 15 GRU steps, h persistent in regs ----------------
__global__ __launch_bounds__(512, 2)
void recur_kernel(const int* __restrict__ x, const u16* __restrict__ xprojP,
                  const u16* __restrict__ Whh_p, const float* __restrict__ b_hh,
                  u16* __restrict__ hidden, float* __restrict__ bnSum, float* __restrict__ bnSumSq,
                  int dir)
{
    __shared__ u16 h_lds[MR*264];     // 64 x 256(+8 pad) bf16 — A-operand staging
    __shared__ float maskv[MR];
    const int tid = threadIdx.x;
    const int mb  = blockIdx.x;       // 0..255
    if (tid < MR) maskv[tid] = (x[mb*MR + tid] > 0) ? 1.0f : 0.0f;
    __syncthreads();

    const int lane = tid & 63, wv = tid >> 6, l31 = lane & 31, q = lane >> 5;
    const int col  = wv*32 + l31;            // hidden column 0..255 (per-lane constant)
    const int bidx = (mb*MR) >> 9;
    const int s0   = (mb*MR) & (NS-1);

    const float bhn = b_hh[2*NH + col];      // only n-gate recurrent bias survives (others folded)

    const u16* ha0 = h_lds + l31*264 + q*8;
    const u16* ha1 = ha0 + 32*264;
    const u16* wb0 = Whh_p + (size_t)(col       )*NH + q*8;
    const u16* wb1 = Whh_p + (size_t)(NH  + col )*NH + q*8;
    const u16* wb2 = Whh_p + (size_t)(2*NH + col)*NH + q*8;

    float hreg[32];
    #pragma unroll
    for (int i = 0; i < 32; i++) hreg[i] = 0.0f;

    #pragma unroll 1
    for (int t = 0; t < NW; t++){
        f32x16 acc[2][3];
        #pragma unroll
        for (int a = 0; a < 2; a++)
            #pragma unroll
            for (int g = 0; g < 3; g++)
                #pragma unroll
                for (int i = 0; i < 16; i++) acc[a][g][i] = (g == 2) ? bhn : 0.0f;

        if (t > 0){
            #pragma unroll 2
            for (int kc = 0; kc < 16; kc++){
                const int ko = kc*16;
                bf16x8 a0 = *(const bf16x8*)(ha0 + ko);
                bf16x8 a1 = *(const bf16x8*)(ha1 + ko);
                bf16x8 b0 = *(const bf16x8*)(wb0 + ko);   // W_hh streamed from L2
                bf16x8 b1 = *(const bf16x8*)(wb1 + ko);
                bf16x8 b2 = *(const bf16x8*)(wb2 + ko);
                acc[0][0] = MFMA32(a0,b0,acc[0][0],0,0,0);
                acc[0][1] = MFMA32(a0,b1,acc[0][1],0,0,0);
                acc[0][2] = MFMA32(a0,b2,acc[0][2],0,0,0);
                acc[1][0] = MFMA32(a1,b0,acc[1][0],0,0,0);
                acc[1][1] = MFMA32(a1,b1,acc[1][1],0,0,0);
                acc[1][2] = MFMA32(a1,b2,acc[1][2],0,0,0);
            }
        }
        // gate phase — full-rate math only: r=sig(xr+hr) z=sig(xz+hz) n=tanh(xn+r*hn)
        const int dscale = (dir == 0) ? (t - (NW-1)) : ((NW-1) - t);
        const int sbase  = s0 + dscale;
        #pragma unroll
        for (int mi = 0; mi < 2; mi++){
            #pragma unroll
            for (int r = 0; r < 16; r++){
                const int rit = (r&3) + 8*(r>>2) + 4*q + mi*32;
                const int j = sbase + rit;
                const int rj = ((unsigned)j < (unsigned)NS) ? (bidx*NS + j) : NCELL; // pad row
                const ushort4 v4 = *(const ushort4*)(xprojP + (size_t)rj*1024 + col*4);
                const float xr = bf2f(v4.x), xz = bf2f(v4.y), xn = bf2f(v4.z);
                const float rg  = sigm_fast(xr + acc[mi][0][r]);
                const float zg  = sigm_fast(xz + acc[mi][1][r]);
                const float ngt = tanh_fast(fmaf(rg, acc[mi][2][r], xn));
                const float hv  = hreg[mi*16+r];
                hreg[mi*16+r] = fmaf(zg, hv - ngt, ngt);   // (1-z)n + z h
            }
        }
        __syncthreads();                       // all A-frag reads of this step done
        #pragma unroll
        for (int mi = 0; mi < 2; mi++)
            #pragma unroll
            for (int r = 0; r < 16; r++){
                const int rit = (r&3) + 8*(r>>2) + 4*q + mi*32;
                h_lds[rit*264 + col] = f2bf_rh(hreg[mi*16+r]);
            }
        __syncthreads();                       // h_lds ready for next step
    }
    // epilogue: mask, store hidden (bf16), BN partial sums
    float sum = 0.0f, sumsq = 0.0f;
    #pragma unroll
    for (int mi = 0; mi < 2; mi++)
        #pragma unroll
        for (int r = 0; r < 16; r++){
            const int rit = (r&3) + 8*(r>>2) + 4*q + mi*32;
            const float hm = hreg[mi*16+r] * maskv[rit];
            hidden[(size_t)(mb*MR + rit)*512 + dir*NH + col] = f2bf(hm);
            sum += hm; sumsq += hm*hm;
        }
    sum   += __shfl_xor(sum, 32);
    sumsq += __shfl_xor(sumsq, 32);
    if (q == 0){
        atomicAdd(&bnSum[dir*NH + col], sum);
        atomicAdd(&bnSumSq[dir*NH + col], sumsq);
    }
}

// ---------------- BN finalize: per-channel scale/shift ----------------
__global__ void bnfin_kernel(const float* __restrict__ bnSum, const float* __restrict__ bnSumSq,
                             const float* __restrict__ gamma, const float* __restrict__ beta,
                             float* __restrict__ bnScale, float* __restrict__ bnShift)
{
    const int c = blockIdx.x*blockDim.x + threadIdx.x;
    if (c < 512){
        const float mu  = bnSum[c]   * (1.0f/16384.0f);
        const float var = bnSumSq[c] * (1.0f/16384.0f) - mu*mu;
        const float inv = rsqrtf(var + 1e-5f);
        const float sc  = gamma[c]*inv;
        bnScale[c] = sc;
        bnShift[c] = beta[c] - mu*sc;
    }
}

// ---------------- MLP + mask + max-pool (atomic ordered-uint max) ----------------
__global__ __launch_bounds__(512, 2)
void mlp_kernel(const int* __restrict__ x, const u16* __restrict__ hidden,
                const u16* __restrict__ mlpW_p, const float* __restrict__ bnScale,
                const float* __restrict__ bnShift, const float* __restrict__ mlp_b,
                unsigned* __restrict__ pooled_u)
{
    __shared__ u16 a_lds[MR*520];   // 64 x 512(+8) bf16 normalized+masked hidden
    __shared__ float maskv[MR];
    const int tid = threadIdx.x;
    const int mb  = blockIdx.x;     // 0..255
    if (tid < MR) maskv[tid] = (x[mb*MR + tid] > 0) ? 1.0f : 0.0f;
    __syncthreads();
    {
        const int row = tid >> 3, jj = tid & 7;
        const float m = maskv[row];
        const u16* src = hidden + (size_t)(mb*MR + row)*512;
        u16* dst = a_lds + row*520;
        for (int c4 = jj; c4 < 128; c4 += 8){
            ushort4 v = ((const ushort4*)src)[c4];
            const int c = c4*4;
            float4 sc = *(const float4*)(bnScale + c);
            float4 sh = *(const float4*)(bnShift + c);
            ushort4 o;
            o.x = f2bf((bf2f(v.x)*sc.x + sh.x)*m);
            o.y = f2bf((bf2f(v.y)*sc.y + sh.y)*m);
            o.z = f2bf((bf2f(v.z)*sc.z + sh.z)*m);
            o.w = f2bf((bf2f(v.w)*sc.w + sh.w)*m);
            *(ushort4*)(dst + c) = o;
        }
    }
    __syncthreads();

    const int lane = tid & 63, wv = tid >> 6, l31 = lane & 31, q = lane >> 5;
    f32x16 acc[2][2];
    #pragma unroll
    for (int a = 0; a < 2; a++)
        #pragma unroll
        for (int g = 0; g < 2; g++)
            #pragma unroll
            for (int i = 0; i < 16; i++) acc[a][g][i] = 0.0f;

    const u16* a0p = a_lds + l31*520 + q*8;
    const u16* a1p = a0p + 32*520;
    const u16* b0p = mlpW_p + (size_t)(wv*64 +      l31)*512 + q*8;
    const u16* b1p = mlpW_p + (size_t)(wv*64 + 32 + l31)*512 + q*8;

    #pragma unroll 4
    for (int kc = 0; kc < 32; kc++){
        const int ko = kc*16;
        bf16x8 a0 = *(const bf16x8*)(a0p + ko);
        bf16x8 a1 = *(const bf16x8*)(a1p + ko);
        bf16x8 b0 = *(const bf16x8*)(b0p + ko);
        bf16x8 b1 = *(const bf16x8*)(b1p + ko);
        acc[0][0] = MFMA32(a0,b0,acc[0][0],0,0,0);
        acc[0][1] = MFMA32(a0,b1,acc[0][1],0,0,0);
        acc[1][0] = MFMA32(a1,b0,acc[1][0],0,0,0);
        acc[1][1] = MFMA32(a1,b1,acc[1][1],0,0,0);
    }

    const int bidx = mb >> 3;   // 8 row-blocks per batch element
    #pragma unroll
    for (int nt = 0; nt < 2; nt++){
        const int colg = wv*64 + nt*32 + l31;
        const float bias = mlp_b[colg];
        float mx = -3.4e38f;
        #pragma unroll
        for (int mi = 0; mi < 2; mi++)
            #pragma unroll
            for (int r = 0; r < 16; r++){
                const int rit = (r&3) + 8*(r>>2) + 4*q + mi*32;
                const float m = maskv[rit];
                const float v = (acc[mi][nt][r] + bias)*m + (m - 1.0f)*65500.0f;
                mx = fmaxf(mx, v);
            }
        mx = fmaxf(mx, __shfl_xor(mx, 32));
        if (q == 0) atomicMax(&pooled_u[bidx*512 + colg], fkey(mx));
    }
}

// ---------------- final linear [32x512] @ [512x2] ----------------
__global__ void final_kernel(const unsigned* __restrict__ pooled_u,
                             const float* __restrict__ linW, const float* __restrict__ linb,
                             float* __restrict__ out)
{
    const int b = blockIdx.x;       // 32
    const int lane = threadIdx.x;   // 64
    float s0 = 0.0f, s1 = 0.0f;
    for (int c = lane; c < 512; c += 64){
        const unsigned u = pooled_u[b*512 + c];
        const unsigned bits = (u & 0x80000000u) ? (u ^ 0x80000000u) : ~u;
        const float f = __uint_as_float(bits);
        s0 += f * linW[c];
        s1 += f * linW[512 + c];
    }
    #pragma unroll
    for (int off = 32; off > 0; off >>= 1){
        s0 += __shfl_xor(s0, off);
        s1 += __shfl_xor(s1, off);
    }
    if (lane == 0){ out[2*b] = s0 + linb[0]; out[2*b + 1] = s1 + linb[1]; }
}

extern "C" void kernel_launch(void* const* d_in, const int* in_sizes, int n_in,
                              void* d_out, int out_size, void* d_ws, size_t ws_size,
                              hipStream_t stream)
{
    const int*   x     = (const int*)  d_in[0];
    const float* emb   = (const float*)d_in[5];
    const float* Wih_f = (const float*)d_in[6];
    const float* Whh_f = (const float*)d_in[7];
    const float* bih_f = (const float*)d_in[8];
    const float* bhh_f = (const float*)d_in[9];
    const float* Wih_b = (const float*)d_in[10];
    const float* Whh_b = (const float*)d_in[11];
    const float* bih_b = (const float*)d_in[12];
    const float* bhh_b = (const float*)d_in[13];
    const float* gamma = (const float*)d_in[14];
    const float* beta  = (const float*)d_in[15];
    const float* mlpW  = (const float*)d_in[16];
    const float* mlpb  = (const float*)d_in[17];
    const float* linW  = (const float*)d_in[18];
    const float* linb  = (const float*)d_in[19];
    float* out = (float*)d_out;
    char* ws = (char*)d_ws;

    // workspace layout (~52.8 MB; xprojP packed [row][col][{r,z,n,0}], shared F then B)
    u16*   WihF_p  = (u16*)  (ws + 0);
    u16*   WihB_p  = (u16*)  (ws + 491520);
    u16*   WhhF_p  = (u16*)  (ws + 983040);
    u16*   WhhB_p  = (u16*)  (ws + 1376256);
    u16*   mlpW_p  = (u16*)  (ws + 1769472);
    float* bnSum   = (float*)(ws + 2293760);
    float* bnSumSq = (float*)(ws + 2295808);
    float* bnScale = (float*)(ws + 2297856);
    float* bnShift = (float*)(ws + 2299904);
    unsigned* pooled_u = (unsigned*)(ws + 2301952);
    u16*   hidden  = (u16*)  (ws + 2367488);    // 16384x512 bf16
    u16*   xprojP  = (u16*)  (ws + 19144704);   // 16448x256x4 bf16 packed

    prep_kernel<<<512, 256, 0, stream>>>(Wih_f, Wih_b, Whh_f, Whh_b, mlpW,
                                         WihF_p, WihB_p, WhhF_p, WhhB_p, mlpW_p,
                                         bnSum, bnSumSq, pooled_u);
    // forward direction
    eproj_kernel<<<257, 512, 0, stream>>>(x, emb, WihF_p, bih_f, bhh_f, xprojP);
    recur_kernel<<<256, 512, 0, stream>>>(x, xprojP, WhhF_p, bhh_f, hidden, bnSum, bnSumSq, 0);
    // backward direction (reuses xprojP buffer)
    eproj_kernel<<<257, 512, 0, stream>>>(x, emb, WihB_p, bih_b, bhh_b, xprojP);
    recur_kernel<<<256, 512, 0, stream>>>(x, xprojP, WhhB_p, bhh_b, hidden, bnSum, bnSumSq, 1);

    bnfin_kernel<<<2, 256, 0, stream>>>(bnSum, bnSumSq, gamma, beta, bnScale, bnShift);
    mlp_kernel<<<256, 512, 0, stream>>>(x, hidden, mlpW_p, bnScale, bnShift, mlpb, pooled_u);
    final_kernel<<<32, 64, 0, stream>>>(pooled_u, linW, linb, out);
}